// Round 9
// baseline (158.607 us; speedup 1.0000x reference)
//
#include <hip/hip_runtime.h>
#include <hip/hip_bf16.h>

#define UNITS 1024
#define EMBED 256
#define TENC  128
#define BATCH 64
#define VOCAB 50257
#define GRU_IN 1280
#define MROWS 8192
#define NCB   8      // col-blocks in k_score (1024/128)
#define NSPLIT 8     // split-K slices for skinny GEMMs

typedef __bf16 bf16x8 __attribute__((ext_vector_type(8)));
typedef float  f32x4  __attribute__((ext_vector_type(4)));
typedef float  f32x4u __attribute__((ext_vector_type(4), aligned(4)));

__device__ __forceinline__ void gload_lds16(const void* gsrc, void* ldst) {
  __builtin_amdgcn_global_load_lds(
      (const __attribute__((address_space(1))) void*)gsrc,
      (__attribute__((address_space(3))) void*)ldst,
      16, 0, 0);
}

// ---------------------------------------------------------------------------
// prep: [0,4096) enc->bf16 ; [4096,4352) W2->bf16 transposed ; [4352,4480)
// q split-K GEMM blocks (hidden @ W1 -> qpart).
// ---------------------------------------------------------------------------
__global__ __launch_bounds__(256) void prep_kernel(
    const float* __restrict__ enc, const float* __restrict__ W2,
    const float* __restrict__ hidden, const float* __restrict__ W1,
    __bf16* __restrict__ encb, __bf16* __restrict__ w2t,
    float* __restrict__ qpart)
{
  __shared__ __bf16 tl[64][72];
  __shared__ __bf16 As[2][4][64][8];
  __shared__ __bf16 Bs[2][4][64][8];
  const int bid = blockIdx.x;
  const int tid = threadIdx.x;

  if (bid < 4096) {                 // enc convert: 4096*256*8 elems
    const size_t base = ((size_t)bid * 256 + tid) * 8;
    const f32x4 v0 = *reinterpret_cast<const f32x4*>(enc + base);
    const f32x4 v1 = *reinterpret_cast<const f32x4*>(enc + base + 4);
    bf16x8 o;
#pragma unroll
    for (int j = 0; j < 4; ++j) { o[j] = (__bf16)v0[j]; o[4 + j] = (__bf16)v1[j]; }
    *reinterpret_cast<bf16x8*>(encb + base) = o;
    return;
  }
  if (bid < 4352) {                 // W2 transpose: 256 tiles of 64x64
    const int ti  = bid - 4096;
    const int kt0 = (ti >> 4) * 64, nt0 = (ti & 15) * 64;
    const int r = tid >> 2, q = (tid & 3) * 16;
    const float* wp = W2 + (size_t)(kt0 + r) * UNITS + nt0 + q;
#pragma unroll
    for (int v = 0; v < 4; ++v) {
      const f32x4 a = *reinterpret_cast<const f32x4*>(wp + v * 4);
#pragma unroll
      for (int j = 0; j < 4; ++j) tl[r][q + v * 4 + j] = (__bf16)a[j];
    }
    __syncthreads();
    const int n = tid >> 2, kq = (tid & 3) * 16;
    bf16x8 o0, o1;
#pragma unroll
    for (int j = 0; j < 8; ++j) { o0[j] = tl[kq + j][n]; o1[j] = tl[kq + 8 + j][n]; }
    __bf16* op = w2t + (size_t)(nt0 + n) * UNITS + kt0 + kq;
    *reinterpret_cast<bf16x8*>(op)     = o0;
    *reinterpret_cast<bf16x8*>(op + 8) = o1;
    return;
  }

  // ---- q split-K: idx -> (col-block 0..15, z 0..7), Kc=128, nt=4
  const int idx   = bid - 4352;
  const int col0  = (idx & 15) * 64;
  const int kbase = (idx >> 4) * 128;
  const int lane = tid & 63;
  const int wid  = tid >> 6;
  const int wm   = (wid >> 1) * 32;
  const int wn   = (wid & 1) * 32;

  f32x4 acc[2][2] = {};
  const int ar  = tid >> 2;
  const int akc = (tid & 3) * 8;
  const int bkk = tid >> 4;
  const int bn  = (tid & 15) * 4;

  f32x4 pa0[2], pa1[2], pb0[2], pb1[2];
  auto LOAD = [&](int k0, int s) {
    const float* ap = hidden + (size_t)ar * UNITS + k0 + akc;
    pa0[s] = *reinterpret_cast<const f32x4*>(ap);
    pa1[s] = *reinterpret_cast<const f32x4*>(ap + 4);
    const float* bp0 = W1 + (size_t)(k0 + bkk) * UNITS + col0 + bn;
    pb0[s] = *reinterpret_cast<const f32x4*>(bp0);
    pb1[s] = *reinterpret_cast<const f32x4*>(bp0 + (size_t)16 * UNITS);
  };
  auto STAGE = [&](int s, int bb) {
    bf16x8 v;
#pragma unroll
    for (int j = 0; j < 4; ++j) { v[j] = (__bf16)pa0[s][j]; v[4 + j] = (__bf16)pa1[s][j]; }
    *reinterpret_cast<bf16x8*>(&As[bb][tid & 3][ar][0]) = v;
#pragma unroll
    for (int j = 0; j < 4; ++j) {
      Bs[bb][bkk >> 3][bn + j][bkk & 7]               = (__bf16)pb0[s][j];
      Bs[bb][(bkk + 16) >> 3][bn + j][(bkk + 16) & 7] = (__bf16)pb1[s][j];
    }
  };
  auto COMPUTE = [&](int bb) {
    bf16x8 af[2], bfr[2];
#pragma unroll
    for (int f = 0; f < 2; ++f) {
      af[f]  = *reinterpret_cast<const bf16x8*>(&As[bb][lane >> 4][wm + f * 16 + (lane & 15)][0]);
      bfr[f] = *reinterpret_cast<const bf16x8*>(&Bs[bb][lane >> 4][wn + f * 16 + (lane & 15)][0]);
    }
#pragma unroll
    for (int fm = 0; fm < 2; ++fm)
#pragma unroll
      for (int fn = 0; fn < 2; ++fn)
        acc[fm][fn] = __builtin_amdgcn_mfma_f32_16x16x32_bf16(af[fm], bfr[fn], acc[fm][fn], 0, 0, 0);
  };

  LOAD(kbase, 0);
  LOAD(kbase + 32, 1);
  STAGE(0, 0);
  __syncthreads();
#pragma unroll 1
  for (int t = 0; t < 4; t += 2) {
    if (t + 2 < 4) LOAD(kbase + ((t + 2) << 5), 0);
    COMPUTE(0);
    STAGE(1, 1);
    __syncthreads();
    if (t + 3 < 4) LOAD(kbase + ((t + 3) << 5), 1);
    COMPUTE(1);
    if (t + 2 < 4) STAGE(0, 0);
    __syncthreads();
  }

  float* Cz = qpart + (size_t)(idx >> 4) * BATCH * UNITS;
#pragma unroll
  for (int fm = 0; fm < 2; ++fm) {
    const int rbase = wm + fm * 16 + (lane >> 4) * 4;
#pragma unroll
    for (int fn = 0; fn < 2; ++fn) {
      const int gc = col0 + wn + fn * 16 + (lane & 15);
#pragma unroll
      for (int r = 0; r < 4; ++r)
        Cz[(size_t)(rbase + r) * UNITS + gc] = acc[fm][fn][r];
    }
  }
}

// ---------------------------------------------------------------------------
// Split-K skinny GEMM (gates): 64x64 tile, dbuf, depth-2 prefetch.
// ---------------------------------------------------------------------------
__global__ __launch_bounds__(256) void gemm_splitk(
    const float* __restrict__ A, const float* __restrict__ B,
    float* __restrict__ Cpart, int M, int N, int K, int Kc)
{
  const int col0  = blockIdx.y * 64;
  const int kbase = blockIdx.z * Kc;
  const int tid  = threadIdx.x;
  const int lane = tid & 63;
  const int wid  = tid >> 6;
  const int wm   = (wid >> 1) * 32;
  const int wn   = (wid & 1) * 32;

  __shared__ __bf16 As[2][4][64][8];
  __shared__ __bf16 Bs[2][4][64][8];

  f32x4 acc[2][2] = {};

  const int ar  = tid >> 2;
  const int akc = (tid & 3) * 8;
  const int bkk = tid >> 4;
  const int bn  = (tid & 15) * 4;

  f32x4 pa0[2], pa1[2], pb0[2], pb1[2];

  auto LOAD = [&](int k0, int s) {
    const float* ap = A + (size_t)ar * K + k0 + akc;
    pa0[s] = *reinterpret_cast<const f32x4*>(ap);
    pa1[s] = *reinterpret_cast<const f32x4*>(ap + 4);
    const float* bp0 = B + (size_t)(k0 + bkk) * N + col0 + bn;
    pb0[s] = *reinterpret_cast<const f32x4*>(bp0);
    pb1[s] = *reinterpret_cast<const f32x4*>(bp0 + (size_t)16 * N);
  };
  auto STAGE = [&](int s, int bb) {
    bf16x8 v;
#pragma unroll
    for (int j = 0; j < 4; ++j) { v[j] = (__bf16)pa0[s][j]; v[4 + j] = (__bf16)pa1[s][j]; }
    *reinterpret_cast<bf16x8*>(&As[bb][tid & 3][ar][0]) = v;
#pragma unroll
    for (int j = 0; j < 4; ++j) {
      Bs[bb][bkk >> 3][bn + j][bkk & 7]               = (__bf16)pb0[s][j];
      Bs[bb][(bkk + 16) >> 3][bn + j][(bkk + 16) & 7] = (__bf16)pb1[s][j];
    }
  };
  auto COMPUTE = [&](int bb) {
    bf16x8 af[2], bfr[2];
#pragma unroll
    for (int f = 0; f < 2; ++f) {
      af[f]  = *reinterpret_cast<const bf16x8*>(&As[bb][lane >> 4][wm + f * 16 + (lane & 15)][0]);
      bfr[f] = *reinterpret_cast<const bf16x8*>(&Bs[bb][lane >> 4][wn + f * 16 + (lane & 15)][0]);
    }
#pragma unroll
    for (int fm = 0; fm < 2; ++fm)
#pragma unroll
      for (int fn = 0; fn < 2; ++fn)
        acc[fm][fn] = __builtin_amdgcn_mfma_f32_16x16x32_bf16(af[fm], bfr[fn], acc[fm][fn], 0, 0, 0);
  };

  const int nt = Kc >> 5;
  LOAD(kbase, 0);
  LOAD(kbase + 32, 1);
  STAGE(0, 0);
  __syncthreads();
  for (int t = 0; t < nt; t += 2) {
    if (t + 2 < nt) LOAD(kbase + ((t + 2) << 5), 0);
    COMPUTE(0);
    if (t + 1 < nt) STAGE(1, 1);
    __syncthreads();
    if (t + 1 < nt) {
      if (t + 3 < nt) LOAD(kbase + ((t + 3) << 5), 1);
      COMPUTE(1);
      if (t + 2 < nt) STAGE(0, 0);
      __syncthreads();
    }
  }

  float* Cz = Cpart + (size_t)blockIdx.z * M * N;
#pragma unroll
  for (int fm = 0; fm < 2; ++fm) {
    const int rbase = wm + fm * 16 + (lane >> 4) * 4;
#pragma unroll
    for (int fn = 0; fn < 2; ++fn) {
      const int gc = col0 + wn + fn * 16 + (lane & 15);
#pragma unroll
      for (int r = 0; r < 4; ++r)
        Cz[(size_t)(rbase + r) * N + gc] = acc[fm][fn][r];
    }
  }
}

// ---------------------------------------------------------------------------
// fc GEMM (unchanged, R5-measured): 64x64 tile, plain loads, dbuf, depth-2,
// nt stores.
// ---------------------------------------------------------------------------
__global__ __launch_bounds__(256) void gemm_fc(
    const float* __restrict__ A, const float* __restrict__ B,
    const float* __restrict__ bias, float* __restrict__ C, int N)
{
  const int col0 = blockIdx.x * 64;
  const int tid  = threadIdx.x;
  const int lane = tid & 63;
  const int wid  = tid >> 6;
  const int wm   = (wid >> 1) * 32;
  const int wn   = (wid & 1) * 32;

  __shared__ __bf16 As[2][4][64][8];
  __shared__ __bf16 Bs[2][4][64][8];

  f32x4 acc[2][2] = {};

  const int ar  = tid >> 2;
  const int akc = (tid & 3) * 8;
  const int bkk = tid >> 4;
  const int bn  = (tid & 15) * 4;
  const int gn  = col0 + bn;
  const bool okb = (gn + 3 < N);

  f32x4 pa0[2], pa1[2], pb0[2], pb1[2];

  auto LOAD = [&](int k0, int s) {
    const float* ap = A + (size_t)ar * UNITS + k0 + akc;
    pa0[s] = *reinterpret_cast<const f32x4*>(ap);
    pa1[s] = *reinterpret_cast<const f32x4*>(ap + 4);
    const float* bp0 = B + (size_t)(k0 + bkk) * N + gn;
    const float* bp1 = bp0 + (size_t)16 * N;
    if (okb) {
      pb0[s] = *reinterpret_cast<const f32x4u*>(bp0);
      pb1[s] = *reinterpret_cast<const f32x4u*>(bp1);
    } else {
      f32x4 t0 = {0,0,0,0}, t1 = {0,0,0,0};
#pragma unroll
      for (int j = 0; j < 4; ++j)
        if (gn + j < N) { t0[j] = bp0[j]; t1[j] = bp1[j]; }
      pb0[s] = t0; pb1[s] = t1;
    }
  };
  auto STAGE = [&](int s, int bb) {
    bf16x8 v;
#pragma unroll
    for (int j = 0; j < 4; ++j) { v[j] = (__bf16)pa0[s][j]; v[4 + j] = (__bf16)pa1[s][j]; }
    *reinterpret_cast<bf16x8*>(&As[bb][tid & 3][ar][0]) = v;
#pragma unroll
    for (int j = 0; j < 4; ++j) {
      Bs[bb][bkk >> 3][bn + j][bkk & 7]               = (__bf16)pb0[s][j];
      Bs[bb][(bkk + 16) >> 3][bn + j][(bkk + 16) & 7] = (__bf16)pb1[s][j];
    }
  };
  auto COMPUTE = [&](int bb) {
    bf16x8 af[2], bfr[2];
#pragma unroll
    for (int f = 0; f < 2; ++f) {
      af[f]  = *reinterpret_cast<const bf16x8*>(&As[bb][lane >> 4][wm + f * 16 + (lane & 15)][0]);
      bfr[f] = *reinterpret_cast<const bf16x8*>(&Bs[bb][lane >> 4][wn + f * 16 + (lane & 15)][0]);
    }
#pragma unroll
    for (int fm = 0; fm < 2; ++fm)
#pragma unroll
      for (int fn = 0; fn < 2; ++fn)
        acc[fm][fn] = __builtin_amdgcn_mfma_f32_16x16x32_bf16(af[fm], bfr[fn], acc[fm][fn], 0, 0, 0);
  };

  LOAD(0, 0);
  LOAD(32, 1);
  STAGE(0, 0);
  __syncthreads();
#pragma unroll 1
  for (int t = 0; t < 32; t += 2) {
    if (t + 2 < 32) LOAD((t + 2) << 5, 0);
    COMPUTE(0);
    STAGE(1, 1);
    __syncthreads();
    if (t + 3 < 32) LOAD((t + 3) << 5, 1);
    COMPUTE(1);
    if (t + 2 < 32) STAGE(0, 0);
    __syncthreads();
  }

#pragma unroll
  for (int fm = 0; fm < 2; ++fm) {
    const int rbase = wm + fm * 16 + (lane >> 4) * 4;
#pragma unroll
    for (int fn = 0; fn < 2; ++fn) {
      const int gc = col0 + wn + fn * 16 + (lane & 15);
      if (gc >= N) continue;
      const float bv = bias[gc];
#pragma unroll
      for (int r = 0; r < 4; ++r)
        __builtin_nontemporal_store(acc[fm][fn][r] + bv, &C[(size_t)(rbase + r) * N + gc]);
    }
  }
}

// ---------------------------------------------------------------------------
// k_score: single-buffer m97 structure (R5-measured) + fcW L3-warm prefetch.
// Prefetch loads are issued AFTER barrier #1 and consumed AFTER the MFMA
// cluster, so the ~1.3µs/iter HBM stream hides under the ~1.4µs MFMA phase
// and completes before barrier #2's vmcnt(0) drain. 512 blocks x 64 x 16B
// = 134MB prefix of fcW warmed into the 256MB Infinity Cache.
// ---------------------------------------------------------------------------
__global__ __launch_bounds__(256) void k_score_mfma(
    const __bf16* __restrict__ encb, const __bf16* __restrict__ w2t,
    const float* __restrict__ b1, const float* __restrict__ b2,
    const float* __restrict__ qpart, const float* __restrict__ Vw,
    const float* __restrict__ fcw, float* __restrict__ pfsink,
    float* __restrict__ partial)
{
  const int b    = blockIdx.x;
  const int row0 = b * TENC;
  const int col0 = blockIdx.y * 128;
  const int tid  = threadIdx.x;
  const int lane = tid & 63;
  const int wid  = tid >> 6;
  const int wm   = (wid >> 1) * 64;
  const int wn   = (wid & 1) * 64;

  __shared__ __bf16 As[8][128][8];   // [k-octet][row][8k]
  __shared__ __bf16 Bs[8][128][8];   // [k-octet][col][8k]
  __shared__ float  sred[2][128];

  f32x4 acc[4][4] = {};

  // prefetch base: block linear id * 65536 floats (256KB per block)
  const size_t pfbase = ((size_t)(b * NCB + blockIdx.y)) * 65536;
  f32x4 pfsum = {0.f, 0.f, 0.f, 0.f};

  for (int t = 0; t < 16; ++t) {
    const int k0 = t * 64;
#pragma unroll
    for (int j = 0; j < 4; ++j) {
      const int i  = wid * 4 + j;
      const int c  = i >> 1, rh = (i & 1) * 64;
      gload_lds16(encb + (size_t)(row0 + rh + lane) * UNITS + k0 + c * 8, &As[c][rh][0]);
      gload_lds16(w2t  + (size_t)(col0 + rh + lane) * UNITS + k0 + c * 8, &Bs[c][rh][0]);
    }
    __syncthreads();   // barrier #1: staged data visible

    // issue fcW prefetch (consumed after MFMAs -> streams under compute)
    f32x4 pf[4];
#pragma unroll
    for (int j = 0; j < 4; ++j)
      pf[j] = *reinterpret_cast<const f32x4*>(
          fcw + pfbase + (size_t)((t * 4 + j) * 256 + tid) * 4);

#pragma unroll
    for (int s = 0; s < 2; ++s) {
      bf16x8 af[4], bfr[4];
#pragma unroll
      for (int f = 0; f < 4; ++f) {
        af[f]  = *reinterpret_cast<const bf16x8*>(&As[s * 4 + (lane >> 4)][wm + f * 16 + (lane & 15)][0]);
        bfr[f] = *reinterpret_cast<const bf16x8*>(&Bs[s * 4 + (lane >> 4)][wn + f * 16 + (lane & 15)][0]);
      }
#pragma unroll
      for (int fm = 0; fm < 4; ++fm)
#pragma unroll
        for (int fn = 0; fn < 4; ++fn)
          acc[fm][fn] = __builtin_amdgcn_mfma_f32_16x16x32_bf16(af[fm], bfr[fn], acc[fm][fn], 0, 0, 0);
    }

    // consume prefetch (keeps loads live; they are complete by now)
#pragma unroll
    for (int j = 0; j < 4; ++j) pfsum += pf[j];

    __syncthreads();   // barrier #2: buffer free for next overwrite
  }

  // sink the prefetch accumulator (deterministic; nobody reads this)
  pfsink[(size_t)(b * NCB + blockIdx.y) * 256 + tid] =
      pfsum[0] + pfsum[1] + pfsum[2] + pfsum[3];

  // fused score epilogue: rowsum = sum_cols tanh(q + b1 + b2 + k) * V
  float rowsum[4][4] = {};
#pragma unroll
  for (int fn = 0; fn < 4; ++fn) {
    const int gc = col0 + wn + fn * 16 + (lane & 15);
    float qv = b1[gc] + b2[gc];
#pragma unroll
    for (int s = 0; s < NSPLIT; ++s)
      qv += qpart[(size_t)s * BATCH * UNITS + (size_t)b * UNITS + gc];
    const float vv = Vw[gc];
#pragma unroll
    for (int fm = 0; fm < 4; ++fm)
#pragma unroll
      for (int r = 0; r < 4; ++r)
        rowsum[fm][r] += tanhf(qv + acc[fm][fn][r]) * vv;
  }
#pragma unroll
  for (int off = 8; off; off >>= 1)
#pragma unroll
    for (int fm = 0; fm < 4; ++fm)
#pragma unroll
      for (int r = 0; r < 4; ++r)
        rowsum[fm][r] += __shfl_xor(rowsum[fm][r], off);
  if ((lane & 15) == 0) {
#pragma unroll
    for (int fm = 0; fm < 4; ++fm)
#pragma unroll
      for (int r = 0; r < 4; ++r)
        sred[wid & 1][wm + fm * 16 + (lane >> 4) * 4 + r] = rowsum[fm][r];
  }
  __syncthreads();
  if (tid < TENC)
    partial[(size_t)blockIdx.y * MROWS + row0 + tid] = sred[0][tid] + sred[1][tid];
}

// ---------------------------------------------------------------------------
// ctx: softmax + context with wave-per-t-slice. grid (64, 16) x 256.
// ---------------------------------------------------------------------------
__global__ __launch_bounds__(256) void ctx_kernel(
    const float* __restrict__ enc, const float* __restrict__ partial,
    const float* __restrict__ bV, const float* __restrict__ emb,
    const int* __restrict__ x, float* __restrict__ attw,
    float* __restrict__ xin)
{
  const int b   = blockIdx.x;
  const int yb  = blockIdx.y;
  const int tid = threadIdx.x;
  const int g   = tid >> 6;        // wave = t-slice
  const int n   = tid & 63;
  __shared__ float scs[TENC];
  __shared__ float red[4];
  __shared__ float csum[4][64];

  if (tid < TENC) {
    float s = bV[0];
#pragma unroll
    for (int cb = 0; cb < NCB; ++cb) s += partial[(size_t)cb * MROWS + b * TENC + tid];
    float m = s;
#pragma unroll
    for (int off = 32; off; off >>= 1) m = fmaxf(m, __shfl_xor(m, off));
    if ((tid & 63) == 0) red[tid >> 6] = m;
    scs[tid] = s;
  }
  __syncthreads();
  const float mm = fmaxf(red[0], red[1]);
  if (tid < TENC) {
    const float e = expf(scs[tid] - mm);
    scs[tid] = e;
    float su = e;
#pragma unroll
    for (int off = 32; off; off >>= 1) su += __shfl_xor(su, off);
    if ((tid & 63) == 0) red[2 + (tid >> 6)] = su;
  }
  __syncthreads();
  const float inv = 1.f / (red[2] + red[3]);

  if (yb == 0 && tid < TENC) attw[(size_t)b * TENC + tid] = scs[tid] * inv;

  const int n0 = yb * 64;
  const float* ep = enc + ((size_t)b * TENC + g * 32) * UNITS + n0 + n;
  float c = 0.f;
#pragma unroll 8
  for (int i = 0; i < 32; ++i) c += scs[g * 32 + i] * ep[(size_t)i * UNITS];
  csum[g][n] = c;
  __syncthreads();
  if (tid < 64)
    xin[(size_t)b * GRU_IN + n0 + tid] =
        (csum[0][tid] + csum[1][tid] + csum[2][tid] + csum[3][tid]) * inv;
  if (yb == 0)
    xin[(size_t)b * GRU_IN + UNITS + tid] = emb[(size_t)x[b] * EMBED + tid];
}

// ---------------------------------------------------------------------------
// GRU pointwise (h0 == 0), summing NSPLIT gate partials + biases.
// ---------------------------------------------------------------------------
__global__ __launch_bounds__(256) void gru_pw(
    const float* __restrict__ gpart, const float* __restrict__ gb0,
    const float* __restrict__ gb1, float* __restrict__ h)
{
  const int i = blockIdx.x * 256 + threadIdx.x;
  const int b = i >> 10, n = i & 1023;
  float xz = gb0[n], xr = gb0[1024 + n], xh = gb0[2048 + n];
#pragma unroll
  for (int s = 0; s < NSPLIT; ++s) {
    const float* g = gpart + (size_t)s * BATCH * 3072 + (size_t)b * 3072;
    xz += g[n]; xr += g[1024 + n]; xh += g[2048 + n];
  }
  const float rz = gb1[n], rr = gb1[1024 + n], rh = gb1[2048 + n];
  const float z = 1.f / (1.f + expf(-(xz + rz)));
  const float r = 1.f / (1.f + expf(-(xr + rr)));
  const float hh = tanhf(xh + r * rh);
  h[i] = (1.f - z) * hh;
}

extern "C" void kernel_launch(void* const* d_in, const int* in_sizes, int n_in,
                              void* d_out, int out_size, void* d_ws, size_t ws_size,
                              hipStream_t stream)
{
  (void)in_sizes; (void)n_in; (void)out_size; (void)ws_size;
  const int*   x      = (const int*)  d_in[0];
  const float* hidden = (const float*)d_in[1];
  const float* enc    = (const float*)d_in[2];
  const float* emb    = (const float*)d_in[3];
  const float* W1     = (const float*)d_in[4];
  const float* b1     = (const float*)d_in[5];
  const float* W2     = (const float*)d_in[6];
  const float* b2     = (const float*)d_in[7];
  const float* Vw     = (const float*)d_in[8];
  const float* bV     = (const float*)d_in[9];
  const float* gk     = (const float*)d_in[10];
  const float* gb     = (const float*)d_in[12];
  const float* fcW    = (const float*)d_in[13];
  const float* fcb    = (const float*)d_in[14];

  float* ws      = (float*)d_ws;
  float* qpart   = ws;                          // 8*64*1024  = 524288 f32
  float* partial = qpart + 524288;              // 8*8192     = 65536
  float* xin     = partial + 65536;             // 64*1280    = 81920
  float* gpart   = xin + 81920;                 // 8*64*3072  = 1572864
  float* pfsink  = gpart + 1572864;             // 512*256    = 131072
  __bf16* encb   = (__bf16*)(pfsink + 131072);  // 8192*1024 bf16
  __bf16* w2t    = encb + (size_t)MROWS * UNITS;// 1024*1024 bf16

  float* out    = (float*)d_out;
  float* logits = out;
  float* hout   = out + (size_t)BATCH * VOCAB;
  float* attw   = hout + BATCH * UNITS;

  // enc->bf16, W2->bf16ᵀ, q split-K partials — one kernel
  hipLaunchKernelGGL(prep_kernel, dim3(4096 + 256 + 128), dim3(256), 0, stream,
                     enc, W2, hidden, W1, encb, w2t, qpart);
  // k-GEMM fused with score partials + fcW L3 prefetch
  hipLaunchKernelGGL(k_score_mfma, dim3(64, NCB), dim3(256), 0, stream,
                     encb, w2t, b1, b2, qpart, Vw, fcW, pfsink, partial);
  // softmax + context + concat
  hipLaunchKernelGGL(ctx_kernel, dim3(64, 16), dim3(256), 0, stream,
                     enc, partial, bV, emb, x, attw, xin);
  // gate partials = xin @ gru_kernel (split-K x8)
  hipLaunchKernelGGL(gemm_splitk, dim3(1, 48, NSPLIT), dim3(256), 0, stream,
                     xin, gk, gpart, 64, 3072, 1280, 160);
  // h (sums gpart + biases)
  hipLaunchKernelGGL(gru_pw, dim3(256), dim3(256), 0, stream,
                     gpart, gb, gb + 3072, hout);
  // logits = h @ fcW + fcb
  hipLaunchKernelGGL(gemm_fc, dim3((VOCAB + 63) / 64), dim3(256), 0, stream,
                     hout, fcW, fcb, logits, VOCAB);
}

// Round 11
// 142.409 us; speedup vs baseline: 1.1137x; 1.1137x over previous
//
#include <hip/hip_runtime.h>
#include <hip/hip_bf16.h>
#include <hip/hip_cooperative_groups.h>

namespace cg = cooperative_groups;

#define UNITS 1024
#define EMBED 256
#define TENC  128
#define BATCH 64
#define VOCAB 50257
#define GRU_IN 1280
#define MROWS 8192
#define NCB   8
#define NSPLIT 8
#define NBLK  512

typedef __bf16 bf16x8 __attribute__((ext_vector_type(8)));
typedef float  f32x4  __attribute__((ext_vector_type(4)));
typedef float  f32x4u __attribute__((ext_vector_type(4), aligned(4)));

__device__ __forceinline__ void gload_lds16(const void* gsrc, void* ldst) {
  __builtin_amdgcn_global_load_lds(
      (const __attribute__((address_space(1))) void*)gsrc,
      (__attribute__((address_space(3))) void*)ldst,
      16, 0, 0);
}

// ===========================================================================
// ======================  STANDALONE (fallback) KERNELS  ====================
// ===========================================================================

__global__ __launch_bounds__(256) void prep_kernel(
    const float* __restrict__ enc, const float* __restrict__ W2,
    const float* __restrict__ hidden, const float* __restrict__ W1,
    __bf16* __restrict__ encb, __bf16* __restrict__ w2t,
    float* __restrict__ qpart)
{
  __shared__ __bf16 tl[64][72];
  __shared__ __bf16 As[2][4][64][8];
  __shared__ __bf16 Bs[2][4][64][8];
  const int bid = blockIdx.x;
  const int tid = threadIdx.x;

  if (bid < 4096) {
    const size_t base = ((size_t)bid * 256 + tid) * 8;
    const f32x4 v0 = *reinterpret_cast<const f32x4*>(enc + base);
    const f32x4 v1 = *reinterpret_cast<const f32x4*>(enc + base + 4);
    bf16x8 o;
#pragma unroll
    for (int j = 0; j < 4; ++j) { o[j] = (__bf16)v0[j]; o[4 + j] = (__bf16)v1[j]; }
    *reinterpret_cast<bf16x8*>(encb + base) = o;
    return;
  }
  if (bid < 4352) {
    const int ti  = bid - 4096;
    const int kt0 = (ti >> 4) * 64, nt0 = (ti & 15) * 64;
    const int r = tid >> 2, q = (tid & 3) * 16;
    const float* wp = W2 + (size_t)(kt0 + r) * UNITS + nt0 + q;
#pragma unroll
    for (int v = 0; v < 4; ++v) {
      const f32x4 a = *reinterpret_cast<const f32x4*>(wp + v * 4);
#pragma unroll
      for (int j = 0; j < 4; ++j) tl[r][q + v * 4 + j] = (__bf16)a[j];
    }
    __syncthreads();
    const int n = tid >> 2, kq = (tid & 3) * 16;
    bf16x8 o0, o1;
#pragma unroll
    for (int j = 0; j < 8; ++j) { o0[j] = tl[kq + j][n]; o1[j] = tl[kq + 8 + j][n]; }
    __bf16* op = w2t + (size_t)(nt0 + n) * UNITS + kt0 + kq;
    *reinterpret_cast<bf16x8*>(op)     = o0;
    *reinterpret_cast<bf16x8*>(op + 8) = o1;
    return;
  }

  const int idx   = bid - 4352;
  const int col0  = (idx & 15) * 64;
  const int kbase = (idx >> 4) * 128;
  const int lane = tid & 63;
  const int wid  = tid >> 6;
  const int wm   = (wid >> 1) * 32;
  const int wn   = (wid & 1) * 32;

  f32x4 acc[2][2] = {};
  const int ar  = tid >> 2;
  const int akc = (tid & 3) * 8;
  const int bkk = tid >> 4;
  const int bn  = (tid & 15) * 4;

  f32x4 pa0[2], pa1[2], pb0[2], pb1[2];
  auto LOAD = [&](int k0, int s) {
    const float* ap = hidden + (size_t)ar * UNITS + k0 + akc;
    pa0[s] = *reinterpret_cast<const f32x4*>(ap);
    pa1[s] = *reinterpret_cast<const f32x4*>(ap + 4);
    const float* bp0 = W1 + (size_t)(k0 + bkk) * UNITS + col0 + bn;
    pb0[s] = *reinterpret_cast<const f32x4*>(bp0);
    pb1[s] = *reinterpret_cast<const f32x4*>(bp0 + (size_t)16 * UNITS);
  };
  auto STAGE = [&](int s, int bb) {
    bf16x8 v;
#pragma unroll
    for (int j = 0; j < 4; ++j) { v[j] = (__bf16)pa0[s][j]; v[4 + j] = (__bf16)pa1[s][j]; }
    *reinterpret_cast<bf16x8*>(&As[bb][tid & 3][ar][0]) = v;
#pragma unroll
    for (int j = 0; j < 4; ++j) {
      Bs[bb][bkk >> 3][bn + j][bkk & 7]               = (__bf16)pb0[s][j];
      Bs[bb][(bkk + 16) >> 3][bn + j][(bkk + 16) & 7] = (__bf16)pb1[s][j];
    }
  };
  auto COMPUTE = [&](int bb) {
    bf16x8 af[2], bfr[2];
#pragma unroll
    for (int f = 0; f < 2; ++f) {
      af[f]  = *reinterpret_cast<const bf16x8*>(&As[bb][lane >> 4][wm + f * 16 + (lane & 15)][0]);
      bfr[f] = *reinterpret_cast<const bf16x8*>(&Bs[bb][lane >> 4][wn + f * 16 + (lane & 15)][0]);
    }
#pragma unroll
    for (int fm = 0; fm < 2; ++fm)
#pragma unroll
      for (int fn = 0; fn < 2; ++fn)
        acc[fm][fn] = __builtin_amdgcn_mfma_f32_16x16x32_bf16(af[fm], bfr[fn], acc[fm][fn], 0, 0, 0);
  };

  LOAD(kbase, 0); LOAD(kbase + 32, 1); STAGE(0, 0);
  __syncthreads();
  LOAD(kbase + 64, 0); COMPUTE(0); STAGE(1, 1);
  __syncthreads();
  LOAD(kbase + 96, 1); COMPUTE(1); STAGE(0, 0);
  __syncthreads();
  COMPUTE(0); STAGE(1, 1);
  __syncthreads();
  COMPUTE(1);

  float* Cz = qpart + (size_t)(idx >> 4) * BATCH * UNITS;
#pragma unroll
  for (int fm = 0; fm < 2; ++fm) {
    const int rbase = wm + fm * 16 + (lane >> 4) * 4;
#pragma unroll
    for (int fn = 0; fn < 2; ++fn) {
      const int gc = col0 + wn + fn * 16 + (lane & 15);
#pragma unroll
      for (int r = 0; r < 4; ++r)
        Cz[(size_t)(rbase + r) * UNITS + gc] = acc[fm][fn][r];
    }
  }
}

__global__ __launch_bounds__(256) void gemm_splitk(
    const float* __restrict__ A, const float* __restrict__ B,
    float* __restrict__ Cpart, int M, int N, int K, int Kc)
{
  const int col0  = blockIdx.y * 64;
  const int kbase = blockIdx.z * Kc;
  const int tid  = threadIdx.x;
  const int lane = tid & 63;
  const int wid  = tid >> 6;
  const int wm   = (wid >> 1) * 32;
  const int wn   = (wid & 1) * 32;

  __shared__ __bf16 As[2][4][64][8];
  __shared__ __bf16 Bs[2][4][64][8];

  f32x4 acc[2][2] = {};
  const int ar  = tid >> 2;
  const int akc = (tid & 3) * 8;
  const int bkk = tid >> 4;
  const int bn  = (tid & 15) * 4;

  f32x4 pa0[2], pa1[2], pb0[2], pb1[2];
  auto LOAD = [&](int k0, int s) {
    const float* ap = A + (size_t)ar * K + k0 + akc;
    pa0[s] = *reinterpret_cast<const f32x4*>(ap);
    pa1[s] = *reinterpret_cast<const f32x4*>(ap + 4);
    const float* bp0 = B + (size_t)(k0 + bkk) * N + col0 + bn;
    pb0[s] = *reinterpret_cast<const f32x4*>(bp0);
    pb1[s] = *reinterpret_cast<const f32x4*>(bp0 + (size_t)16 * N);
  };
  auto STAGE = [&](int s, int bb) {
    bf16x8 v;
#pragma unroll
    for (int j = 0; j < 4; ++j) { v[j] = (__bf16)pa0[s][j]; v[4 + j] = (__bf16)pa1[s][j]; }
    *reinterpret_cast<bf16x8*>(&As[bb][tid & 3][ar][0]) = v;
#pragma unroll
    for (int j = 0; j < 4; ++j) {
      Bs[bb][bkk >> 3][bn + j][bkk & 7]               = (__bf16)pb0[s][j];
      Bs[bb][(bkk + 16) >> 3][bn + j][(bkk + 16) & 7] = (__bf16)pb1[s][j];
    }
  };
  auto COMPUTE = [&](int bb) {
    bf16x8 af[2], bfr[2];
#pragma unroll
    for (int f = 0; f < 2; ++f) {
      af[f]  = *reinterpret_cast<const bf16x8*>(&As[bb][lane >> 4][wm + f * 16 + (lane & 15)][0]);
      bfr[f] = *reinterpret_cast<const bf16x8*>(&Bs[bb][lane >> 4][wn + f * 16 + (lane & 15)][0]);
    }
#pragma unroll
    for (int fm = 0; fm < 2; ++fm)
#pragma unroll
      for (int fn = 0; fn < 2; ++fn)
        acc[fm][fn] = __builtin_amdgcn_mfma_f32_16x16x32_bf16(af[fm], bfr[fn], acc[fm][fn], 0, 0, 0);
  };

  const int nt = Kc >> 5;
  LOAD(kbase, 0); LOAD(kbase + 32, 1); STAGE(0, 0);
  __syncthreads();
  for (int t = 0; t < nt; t += 2) {
    if (t + 2 < nt) LOAD(kbase + ((t + 2) << 5), 0);
    COMPUTE(0);
    if (t + 1 < nt) STAGE(1, 1);
    __syncthreads();
    if (t + 1 < nt) {
      if (t + 3 < nt) LOAD(kbase + ((t + 3) << 5), 1);
      COMPUTE(1);
      if (t + 2 < nt) STAGE(0, 0);
      __syncthreads();
    }
  }

  float* Cz = Cpart + (size_t)blockIdx.z * M * N;
#pragma unroll
  for (int fm = 0; fm < 2; ++fm) {
    const int rbase = wm + fm * 16 + (lane >> 4) * 4;
#pragma unroll
    for (int fn = 0; fn < 2; ++fn) {
      const int gc = col0 + wn + fn * 16 + (lane & 15);
#pragma unroll
      for (int r = 0; r < 4; ++r)
        Cz[(size_t)(rbase + r) * N + gc] = acc[fm][fn][r];
    }
  }
}

__global__ __launch_bounds__(256) void gemm_fc(
    const float* __restrict__ A, const float* __restrict__ B,
    const float* __restrict__ bias, float* __restrict__ C, int N)
{
  const int col0 = blockIdx.x * 64;
  const int tid  = threadIdx.x;
  const int lane = tid & 63;
  const int wid  = tid >> 6;
  const int wm   = (wid >> 1) * 32;
  const int wn   = (wid & 1) * 32;

  __shared__ __bf16 As[2][4][64][8];
  __shared__ __bf16 Bs[2][4][64][8];

  f32x4 acc[2][2] = {};
  const int ar  = tid >> 2;
  const int akc = (tid & 3) * 8;
  const int bkk = tid >> 4;
  const int bn  = (tid & 15) * 4;
  const int gn  = col0 + bn;
  const bool okb = (gn + 3 < N);

  f32x4 pa0[2], pa1[2], pb0[2], pb1[2];
  auto LOAD = [&](int k0, int s) {
    const float* ap = A + (size_t)ar * UNITS + k0 + akc;
    pa0[s] = *reinterpret_cast<const f32x4*>(ap);
    pa1[s] = *reinterpret_cast<const f32x4*>(ap + 4);
    const float* bp0 = B + (size_t)(k0 + bkk) * N + gn;
    const float* bp1 = bp0 + (size_t)16 * N;
    if (okb) {
      pb0[s] = *reinterpret_cast<const f32x4u*>(bp0);
      pb1[s] = *reinterpret_cast<const f32x4u*>(bp1);
    } else {
      f32x4 t0 = {0,0,0,0}, t1 = {0,0,0,0};
#pragma unroll
      for (int j = 0; j < 4; ++j)
        if (gn + j < N) { t0[j] = bp0[j]; t1[j] = bp1[j]; }
      pb0[s] = t0; pb1[s] = t1;
    }
  };
  auto STAGE = [&](int s, int bb) {
    bf16x8 v;
#pragma unroll
    for (int j = 0; j < 4; ++j) { v[j] = (__bf16)pa0[s][j]; v[4 + j] = (__bf16)pa1[s][j]; }
    *reinterpret_cast<bf16x8*>(&As[bb][tid & 3][ar][0]) = v;
#pragma unroll
    for (int j = 0; j < 4; ++j) {
      Bs[bb][bkk >> 3][bn + j][bkk & 7]               = (__bf16)pb0[s][j];
      Bs[bb][(bkk + 16) >> 3][bn + j][(bkk + 16) & 7] = (__bf16)pb1[s][j];
    }
  };
  auto COMPUTE = [&](int bb) {
    bf16x8 af[2], bfr[2];
#pragma unroll
    for (int f = 0; f < 2; ++f) {
      af[f]  = *reinterpret_cast<const bf16x8*>(&As[bb][lane >> 4][wm + f * 16 + (lane & 15)][0]);
      bfr[f] = *reinterpret_cast<const bf16x8*>(&Bs[bb][lane >> 4][wn + f * 16 + (lane & 15)][0]);
    }
#pragma unroll
    for (int fm = 0; fm < 2; ++fm)
#pragma unroll
      for (int fn = 0; fn < 2; ++fn)
        acc[fm][fn] = __builtin_amdgcn_mfma_f32_16x16x32_bf16(af[fm], bfr[fn], acc[fm][fn], 0, 0, 0);
  };

  LOAD(0, 0); LOAD(32, 1); STAGE(0, 0);
  __syncthreads();
#pragma unroll 1
  for (int t = 0; t < 32; t += 2) {
    if (t + 2 < 32) LOAD((t + 2) << 5, 0);
    COMPUTE(0);
    STAGE(1, 1);
    __syncthreads();
    if (t + 3 < 32) LOAD((t + 3) << 5, 1);
    COMPUTE(1);
    if (t + 2 < 32) STAGE(0, 0);
    __syncthreads();
  }

#pragma unroll
  for (int fm = 0; fm < 2; ++fm) {
    const int rbase = wm + fm * 16 + (lane >> 4) * 4;
#pragma unroll
    for (int fn = 0; fn < 2; ++fn) {
      const int gc = col0 + wn + fn * 16 + (lane & 15);
      if (gc >= N) continue;
      const float bv = bias[gc];
#pragma unroll
      for (int r = 0; r < 4; ++r)
        __builtin_nontemporal_store(acc[fm][fn][r] + bv, &C[(size_t)(rbase + r) * N + gc]);
    }
  }
}

__global__ __launch_bounds__(256) void k_score_mfma(
    const __bf16* __restrict__ encb, const __bf16* __restrict__ w2t,
    const float* __restrict__ b1, const float* __restrict__ b2,
    const float* __restrict__ qpart, const float* __restrict__ Vw,
    float* __restrict__ partial)
{
  const int b    = blockIdx.x;
  const int row0 = b * TENC;
  const int col0 = blockIdx.y * 128;
  const int tid  = threadIdx.x;
  const int lane = tid & 63;
  const int wid  = tid >> 6;
  const int wm   = (wid >> 1) * 64;
  const int wn   = (wid & 1) * 64;

  __shared__ __bf16 As[8][128][8];
  __shared__ __bf16 Bs[8][128][8];
  __shared__ float  sred[2][128];

  f32x4 acc[4][4] = {};

  for (int t = 0; t < 16; ++t) {
    const int k0 = t * 64;
#pragma unroll
    for (int j = 0; j < 4; ++j) {
      const int i  = wid * 4 + j;
      const int c  = i >> 1, rh = (i & 1) * 64;
      gload_lds16(encb + (size_t)(row0 + rh + lane) * UNITS + k0 + c * 8, &As[c][rh][0]);
      gload_lds16(w2t  + (size_t)(col0 + rh + lane) * UNITS + k0 + c * 8, &Bs[c][rh][0]);
    }
    __syncthreads();
#pragma unroll
    for (int s = 0; s < 2; ++s) {
      bf16x8 af[4], bfr[4];
#pragma unroll
      for (int f = 0; f < 4; ++f) {
        af[f]  = *reinterpret_cast<const bf16x8*>(&As[s * 4 + (lane >> 4)][wm + f * 16 + (lane & 15)][0]);
        bfr[f] = *reinterpret_cast<const bf16x8*>(&Bs[s * 4 + (lane >> 4)][wn + f * 16 + (lane & 15)][0]);
      }
#pragma unroll
      for (int fm = 0; fm < 4; ++fm)
#pragma unroll
        for (int fn = 0; fn < 4; ++fn)
          acc[fm][fn] = __builtin_amdgcn_mfma_f32_16x16x32_bf16(af[fm], bfr[fn], acc[fm][fn], 0, 0, 0);
    }
    __syncthreads();
  }

  float rowsum[4][4] = {};
#pragma unroll
  for (int fn = 0; fn < 4; ++fn) {
    const int gc = col0 + wn + fn * 16 + (lane & 15);
    float qv = b1[gc] + b2[gc];
#pragma unroll
    for (int s = 0; s < NSPLIT; ++s)
      qv += qpart[(size_t)s * BATCH * UNITS + (size_t)b * UNITS + gc];
    const float vv = Vw[gc];
#pragma unroll
    for (int fm = 0; fm < 4; ++fm)
#pragma unroll
      for (int r = 0; r < 4; ++r)
        rowsum[fm][r] += tanhf(qv + acc[fm][fn][r]) * vv;
  }
#pragma unroll
  for (int off = 8; off; off >>= 1)
#pragma unroll
    for (int fm = 0; fm < 4; ++fm)
#pragma unroll
      for (int r = 0; r < 4; ++r)
        rowsum[fm][r] += __shfl_xor(rowsum[fm][r], off);
  if ((lane & 15) == 0) {
#pragma unroll
    for (int fm = 0; fm < 4; ++fm)
#pragma unroll
      for (int r = 0; r < 4; ++r)
        sred[wid & 1][wm + fm * 16 + (lane >> 4) * 4 + r] = rowsum[fm][r];
  }
  __syncthreads();
  if (tid < TENC)
    partial[(size_t)blockIdx.y * MROWS + row0 + tid] = sred[0][tid] + sred[1][tid];
}

__global__ __launch_bounds__(256) void ctx_kernel(
    const float* __restrict__ enc, const float* __restrict__ partial,
    const float* __restrict__ bV, const float* __restrict__ emb,
    const int* __restrict__ x, float* __restrict__ attw,
    float* __restrict__ xin)
{
  const int b   = blockIdx.x;
  const int yb  = blockIdx.y;
  const int tid = threadIdx.x;
  const int g   = tid >> 6;
  const int n   = tid & 63;
  __shared__ float scs[TENC];
  __shared__ float red[4];
  __shared__ float csum[4][64];

  if (tid < TENC) {
    float s = bV[0];
#pragma unroll
    for (int cb = 0; cb < NCB; ++cb) s += partial[(size_t)cb * MROWS + b * TENC + tid];
    float m = s;
#pragma unroll
    for (int off = 32; off; off >>= 1) m = fmaxf(m, __shfl_xor(m, off));
    if ((tid & 63) == 0) red[tid >> 6] = m;
    scs[tid] = s;
  }
  __syncthreads();
  const float mm = fmaxf(red[0], red[1]);
  if (tid < TENC) {
    const float e = expf(scs[tid] - mm);
    scs[tid] = e;
    float su = e;
#pragma unroll
    for (int off = 32; off; off >>= 1) su += __shfl_xor(su, off);
    if ((tid & 63) == 0) red[2 + (tid >> 6)] = su;
  }
  __syncthreads();
  const float inv = 1.f / (red[2] + red[3]);

  if (yb == 0 && tid < TENC) attw[(size_t)b * TENC + tid] = scs[tid] * inv;

  const int n0 = yb * 64;
  const float* ep = enc + ((size_t)b * TENC + g * 32) * UNITS + n0 + n;
  float c = 0.f;
#pragma unroll 8
  for (int i = 0; i < 32; ++i) c += scs[g * 32 + i] * ep[(size_t)i * UNITS];
  csum[g][n] = c;
  __syncthreads();
  if (tid < 64)
    xin[(size_t)b * GRU_IN + n0 + tid] =
        (csum[0][tid] + csum[1][tid] + csum[2][tid] + csum[3][tid]) * inv;
  if (yb == 0)
    xin[(size_t)b * GRU_IN + UNITS + tid] = emb[(size_t)x[b] * EMBED + tid];
}

__global__ __launch_bounds__(256) void gru_pw(
    const float* __restrict__ gpart, const float* __restrict__ gb0,
    const float* __restrict__ gb1, float* __restrict__ h)
{
  const int i = blockIdx.x * 256 + threadIdx.x;
  const int b = i >> 10, n = i & 1023;
  float xz = gb0[n], xr = gb0[1024 + n], xh = gb0[2048 + n];
#pragma unroll
  for (int s = 0; s < NSPLIT; ++s) {
    const float* g = gpart + (size_t)s * BATCH * 3072 + (size_t)b * 3072;
    xz += g[n]; xr += g[1024 + n]; xh += g[2048 + n];
  }
  const float rz = gb1[n], rr = gb1[1024 + n], rh = gb1[2048 + n];
  const float z = 1.f / (1.f + expf(-(xz + rz)));
  const float r = 1.f / (1.f + expf(-(xr + rr)));
  const float hh = tanhf(xh + r * rh);
  h[i] = (1.f - z) * hh;
}

// ===========================================================================
// ==========================  COOPERATIVE MEGA  =============================
// ===========================================================================

union SMem {
  struct { __bf16 A[8][128][8]; __bf16 B[8][128][8]; float sred[2][128]; } ks;
  struct { __bf16 A[2][4][64][8]; __bf16 B[2][4][64][8]; } gm;
  struct { __bf16 tl[64][72]; } tr;
  struct { float scs[TENC]; float red[4]; float csum[4][64]; } cx;
};

__global__ __launch_bounds__(256, 2) void mega_kernel(
    const int* __restrict__ x, const float* __restrict__ hidden,
    const float* __restrict__ enc, const float* __restrict__ emb,
    const float* __restrict__ W1, const float* __restrict__ b1,
    const float* __restrict__ W2, const float* __restrict__ b2,
    const float* __restrict__ Vw, const float* __restrict__ bV,
    const float* __restrict__ gk, const float* __restrict__ gb,
    const float* __restrict__ fcW, const float* __restrict__ fcb,
    __bf16* __restrict__ encb, __bf16* __restrict__ w2t,
    float* __restrict__ qpart, float* __restrict__ partial,
    float* __restrict__ xin, float* __restrict__ gpart,
    float* __restrict__ logits, float* __restrict__ hout,
    float* __restrict__ attw)
{
  __shared__ SMem sm;
  cg::grid_group grid = cg::this_grid();
  const int bid  = blockIdx.x;
  const int tid  = threadIdx.x;
  const int lane = tid & 63;
  const int wid  = tid >> 6;
  const int nblk = gridDim.x;

  // -------- Phase A: prep --------
  for (int item = bid; item < 4480; item += nblk) {
    if (item < 4096) {
      const size_t base = ((size_t)item * 256 + tid) * 8;
      const f32x4 v0 = *reinterpret_cast<const f32x4*>(enc + base);
      const f32x4 v1 = *reinterpret_cast<const f32x4*>(enc + base + 4);
      bf16x8 o;
#pragma unroll
      for (int j = 0; j < 4; ++j) { o[j] = (__bf16)v0[j]; o[4 + j] = (__bf16)v1[j]; }
      *reinterpret_cast<bf16x8*>(encb + base) = o;
    } else if (item < 4352) {
      __syncthreads();
      const int ti  = item - 4096;
      const int kt0 = (ti >> 4) * 64, nt0 = (ti & 15) * 64;
      const int r = tid >> 2, q = (tid & 3) * 16;
      const float* wp = W2 + (size_t)(kt0 + r) * UNITS + nt0 + q;
#pragma unroll
      for (int v = 0; v < 4; ++v) {
        const f32x4 a = *reinterpret_cast<const f32x4*>(wp + v * 4);
#pragma unroll
        for (int j = 0; j < 4; ++j) sm.tr.tl[r][q + v * 4 + j] = (__bf16)a[j];
      }
      __syncthreads();
      const int n = tid >> 2, kq = (tid & 3) * 16;
      bf16x8 o0, o1;
#pragma unroll
      for (int j = 0; j < 8; ++j) { o0[j] = sm.tr.tl[kq + j][n]; o1[j] = sm.tr.tl[kq + 8 + j][n]; }
      __bf16* op = w2t + (size_t)(nt0 + n) * UNITS + kt0 + kq;
      *reinterpret_cast<bf16x8*>(op)     = o0;
      *reinterpret_cast<bf16x8*>(op + 8) = o1;
    } else {
      __syncthreads();
      const int idx   = item - 4352;
      const int col0  = (idx & 15) * 64;
      const int kbase = (idx >> 4) * 128;
      const int wm = (wid >> 1) * 32, wn = (wid & 1) * 32;
      f32x4 acc[2][2] = {};
      const int ar  = tid >> 2;
      const int akc = (tid & 3) * 8;
      const int bkk = tid >> 4;
      const int bn  = (tid & 15) * 4;
      f32x4 pa0[2], pa1[2], pb0[2], pb1[2];
      auto LOAD = [&](int k0, int s) {
        const float* ap = hidden + (size_t)ar * UNITS + k0 + akc;
        pa0[s] = *reinterpret_cast<const f32x4*>(ap);
        pa1[s] = *reinterpret_cast<const f32x4*>(ap + 4);
        const float* bp0 = W1 + (size_t)(k0 + bkk) * UNITS + col0 + bn;
        pb0[s] = *reinterpret_cast<const f32x4*>(bp0);
        pb1[s] = *reinterpret_cast<const f32x4*>(bp0 + (size_t)16 * UNITS);
      };
      auto STAGE = [&](int s, int bb) {
        bf16x8 v;
#pragma unroll
        for (int j = 0; j < 4; ++j) { v[j] = (__bf16)pa0[s][j]; v[4 + j] = (__bf16)pa1[s][j]; }
        *reinterpret_cast<bf16x8*>(&sm.gm.A[bb][tid & 3][ar][0]) = v;
#pragma unroll
        for (int j = 0; j < 4; ++j) {
          sm.gm.B[bb][bkk >> 3][bn + j][bkk & 7]               = (__bf16)pb0[s][j];
          sm.gm.B[bb][(bkk + 16) >> 3][bn + j][(bkk + 16) & 7] = (__bf16)pb1[s][j];
        }
      };
      auto COMPUTE = [&](int bb) {
        bf16x8 af[2], bfr[2];
#pragma unroll
        for (int f = 0; f < 2; ++f) {
          af[f]  = *reinterpret_cast<const bf16x8*>(&sm.gm.A[bb][lane >> 4][wm + f * 16 + (lane & 15)][0]);
          bfr[f] = *reinterpret_cast<const bf16x8*>(&sm.gm.B[bb][lane >> 4][wn + f * 16 + (lane & 15)][0]);
        }
#pragma unroll
        for (int fm = 0; fm < 2; ++fm)
#pragma unroll
          for (int fn = 0; fn < 2; ++fn)
            acc[fm][fn] = __builtin_amdgcn_mfma_f32_16x16x32_bf16(af[fm], bfr[fn], acc[fm][fn], 0, 0, 0);
      };
      LOAD(kbase, 0); LOAD(kbase + 32, 1); STAGE(0, 0);
      __syncthreads();
      LOAD(kbase + 64, 0); COMPUTE(0); STAGE(1, 1);
      __syncthreads();
      LOAD(kbase + 96, 1); COMPUTE(1); STAGE(0, 0);
      __syncthreads();
      COMPUTE(0); STAGE(1, 1);
      __syncthreads();
      COMPUTE(1);
      float* Cz = qpart + (size_t)(idx >> 4) * BATCH * UNITS;
#pragma unroll
      for (int fm = 0; fm < 2; ++fm) {
        const int rbase = wm + fm * 16 + (lane >> 4) * 4;
#pragma unroll
        for (int fn = 0; fn < 2; ++fn) {
          const int gc = col0 + wn + fn * 16 + (lane & 15);
#pragma unroll
          for (int r = 0; r < 4; ++r)
            Cz[(size_t)(rbase + r) * UNITS + gc] = acc[fm][fn][r];
        }
      }
    }
  }
  __threadfence();
  grid.sync();

  // -------- Phase B: k_score --------
  for (int item = bid; item < 512; item += nblk) {
    __syncthreads();
    const int b    = item & 63;
    const int cb   = item >> 6;
    const int row0 = b * TENC;
    const int col0 = cb * 128;
    const int wm = (wid >> 1) * 64, wn = (wid & 1) * 64;
    f32x4 acc[4][4] = {};

    for (int t = 0; t < 16; ++t) {
      const int k0 = t * 64;
#pragma unroll
      for (int j = 0; j < 4; ++j) {
        const int i  = wid * 4 + j;
        const int c  = i >> 1, rh = (i & 1) * 64;
        gload_lds16(encb + (size_t)(row0 + rh + lane) * UNITS + k0 + c * 8, &sm.ks.A[c][rh][0]);
        gload_lds16(w2t  + (size_t)(col0 + rh + lane) * UNITS + k0 + c * 8, &sm.ks.B[c][rh][0]);
      }
      __syncthreads();
#pragma unroll
      for (int s = 0; s < 2; ++s) {
        bf16x8 af[4], bfr[4];
#pragma unroll
        for (int f = 0; f < 4; ++f) {
          af[f]  = *reinterpret_cast<const bf16x8*>(&sm.ks.A[s * 4 + (lane >> 4)][wm + f * 16 + (lane & 15)][0]);
          bfr[f] = *reinterpret_cast<const bf16x8*>(&sm.ks.B[s * 4 + (lane >> 4)][wn + f * 16 + (lane & 15)][0]);
        }
#pragma unroll
        for (int fm = 0; fm < 4; ++fm)
#pragma unroll
          for (int fn = 0; fn < 4; ++fn)
            acc[fm][fn] = __builtin_amdgcn_mfma_f32_16x16x32_bf16(af[fm], bfr[fn], acc[fm][fn], 0, 0, 0);
      }
      __syncthreads();
    }

    float rowsum[4][4] = {};
#pragma unroll
    for (int fn = 0; fn < 4; ++fn) {
      const int gc = col0 + wn + fn * 16 + (lane & 15);
      float qv = b1[gc] + b2[gc];
#pragma unroll
      for (int s = 0; s < NSPLIT; ++s)
        qv += qpart[(size_t)s * BATCH * UNITS + (size_t)b * UNITS + gc];
      const float vv = Vw[gc];
#pragma unroll
      for (int fm = 0; fm < 4; ++fm)
#pragma unroll
        for (int r = 0; r < 4; ++r)
          rowsum[fm][r] += tanhf(qv + acc[fm][fn][r]) * vv;
    }
#pragma unroll
    for (int off = 8; off; off >>= 1)
#pragma unroll
      for (int fm = 0; fm < 4; ++fm)
#pragma unroll
        for (int r = 0; r < 4; ++r)
          rowsum[fm][r] += __shfl_xor(rowsum[fm][r], off);
    if ((lane & 15) == 0) {
#pragma unroll
      for (int fm = 0; fm < 4; ++fm)
#pragma unroll
        for (int r = 0; r < 4; ++r)
          sm.ks.sred[wid & 1][wm + fm * 16 + (lane >> 4) * 4 + r] = rowsum[fm][r];
    }
    __syncthreads();
    if (tid < TENC)
      partial[(size_t)cb * MROWS + row0 + tid] = sm.ks.sred[0][tid] + sm.ks.sred[1][tid];
  }
  __threadfence();
  grid.sync();

  // -------- Phase C: softmax + context + concat --------
  for (int item = bid; item < 1024; item += nblk) {
    __syncthreads();
    const int b  = item & 63;
    const int yb = item >> 6;
    const int gq = tid >> 6;
    const int n  = tid & 63;
    if (tid < TENC) {
      float s = bV[0];
#pragma unroll
      for (int cb = 0; cb < NCB; ++cb) s += partial[(size_t)cb * MROWS + b * TENC + tid];
      float m = s;
#pragma unroll
      for (int off = 32; off; off >>= 1) m = fmaxf(m, __shfl_xor(m, off));
      if ((tid & 63) == 0) sm.cx.red[tid >> 6] = m;
      sm.cx.scs[tid] = s;
    }
    __syncthreads();
    const float mm = fmaxf(sm.cx.red[0], sm.cx.red[1]);
    if (tid < TENC) {
      const float e = expf(sm.cx.scs[tid] - mm);
      sm.cx.scs[tid] = e;
      float su = e;
#pragma unroll
      for (int off = 32; off; off >>= 1) su += __shfl_xor(su, off);
      if ((tid & 63) == 0) sm.cx.red[2 + (tid >> 6)] = su;
    }
    __syncthreads();
    const float inv = 1.f / (sm.cx.red[2] + sm.cx.red[3]);
    if (yb == 0 && tid < TENC) attw[(size_t)b * TENC + tid] = sm.cx.scs[tid] * inv;

    const int n0 = yb * 64;
    const float* ep = enc + ((size_t)b * TENC + gq * 32) * UNITS + n0 + n;
    float c = 0.f;
#pragma unroll 8
    for (int i = 0; i < 32; ++i) c += sm.cx.scs[gq * 32 + i] * ep[(size_t)i * UNITS];
    sm.cx.csum[gq][n] = c;
    __syncthreads();
    if (tid < 64)
      xin[(size_t)b * GRU_IN + n0 + tid] =
          (sm.cx.csum[0][tid] + sm.cx.csum[1][tid] + sm.cx.csum[2][tid] + sm.cx.csum[3][tid]) * inv;
    if (yb == 0)
      xin[(size_t)b * GRU_IN + UNITS + tid] = emb[(size_t)x[b] * EMBED + tid];
  }
  __threadfence();
  grid.sync();

  // -------- Phase D: gates split-K --------
  for (int item = bid; item < 384; item += nblk) {
    __syncthreads();
    const int y = item % 48, z = item / 48;
    const int col0 = y * 64, kbase = z * 160;
    const int wm = (wid >> 1) * 32, wn = (wid & 1) * 32;
    f32x4 acc[2][2] = {};
    const int ar  = tid >> 2;
    const int akc = (tid & 3) * 8;
    const int bkk = tid >> 4;
    const int bn  = (tid & 15) * 4;
    f32x4 pa0[2], pa1[2], pb0[2], pb1[2];
    auto LOAD = [&](int k0, int s) {
      const float* ap = xin + (size_t)ar * GRU_IN + k0 + akc;
      pa0[s] = *reinterpret_cast<const f32x4*>(ap);
      pa1[s] = *reinterpret_cast<const f32x4*>(ap + 4);
      const float* bp0 = gk + (size_t)(k0 + bkk) * 3072 + col0 + bn;
      pb0[s] = *reinterpret_cast<const f32x4*>(bp0);
      pb1[s] = *reinterpret_cast<const f32x4*>(bp0 + (size_t)16 * 3072);
    };
    auto STAGE = [&](int s, int bb) {
      bf16x8 v;
#pragma unroll
      for (int j = 0; j < 4; ++j) { v[j] = (__bf16)pa0[s][j]; v[4 + j] = (__bf16)pa1[s][j]; }
      *reinterpret_cast<bf16x8*>(&sm.gm.A[bb][tid & 3][ar][0]) = v;
#pragma unroll
      for (int j = 0; j < 4; ++j) {
        sm.gm.B[bb][bkk >> 3][bn + j][bkk & 7]               = (__bf16)pb0[s][j];
        sm.gm.B[bb][(bkk + 16) >> 3][bn + j][(bkk + 16) & 7] = (__bf16)pb1[s][j];
      }
    };
    auto COMPUTE = [&](int bb) {
      bf16x8 af[2], bfr[2];
#pragma unroll
      for (int f = 0; f < 2; ++f) {
        af[f]  = *reinterpret_cast<const bf16x8*>(&sm.gm.A[bb][lane >> 4][wm + f * 16 + (lane & 15)][0]);
        bfr[f] = *reinterpret_cast<const bf16x8*>(&sm.gm.B[bb][lane >> 4][wn + f * 16 + (lane & 15)][0]);
      }
#pragma unroll
      for (int fm = 0; fm < 2; ++fm)
#pragma unroll
        for (int fn = 0; fn < 2; ++fn)
          acc[fm][fn] = __builtin_amdgcn_mfma_f32_16x16x32_bf16(af[fm], bfr[fn], acc[fm][fn], 0, 0, 0);
    };
    LOAD(kbase, 0); LOAD(kbase + 32, 1); STAGE(0, 0);
    __syncthreads();
    for (int t = 0; t < 5; t += 2) {
      if (t + 2 < 5) LOAD(kbase + ((t + 2) << 5), 0);
      COMPUTE(0);
      if (t + 1 < 5) STAGE(1, 1);
      __syncthreads();
      if (t + 1 < 5) {
        if (t + 3 < 5) LOAD(kbase + ((t + 3) << 5), 1);
        COMPUTE(1);
        if (t + 2 < 5) STAGE(0, 0);
        __syncthreads();
      }
    }
    float* Cz = gpart + (size_t)z * BATCH * 3072;
#pragma unroll
    for (int fm = 0; fm < 2; ++fm) {
      const int rbase = wm + fm * 16 + (lane >> 4) * 4;
#pragma unroll
      for (int fn = 0; fn < 2; ++fn) {
        const int gc = col0 + wn + fn * 16 + (lane & 15);
#pragma unroll
        for (int r = 0; r < 4; ++r)
          Cz[(size_t)(rbase + r) * 3072 + gc] = acc[fm][fn][r];
      }
    }
  }
  __threadfence();
  grid.sync();

  // -------- Phase E: GRU pointwise --------
  for (int item = bid; item < 256; item += nblk) {
    const int i = item * 256 + tid;
    const int b = i >> 10, n = i & 1023;
    float xz = gb[n], xr = gb[1024 + n], xh = gb[2048 + n];
#pragma unroll
    for (int s = 0; s < NSPLIT; ++s) {
      const float* g = gpart + (size_t)s * BATCH * 3072 + (size_t)b * 3072;
      xz += g[n]; xr += g[1024 + n]; xh += g[2048 + n];
    }
    const float* gb1p = gb + 3072;
    const float rz = gb1p[n], rr = gb1p[1024 + n], rh = gb1p[2048 + n];
    const float z = 1.f / (1.f + expf(-(xz + rz)));
    const float r = 1.f / (1.f + expf(-(xr + rr)));
    const float hh = tanhf(xh + r * rh);
    hout[i] = (1.f - z) * hh;
  }
  __threadfence();
  grid.sync();

  // -------- Phase F: fc GEMM --------
  for (int item = bid; item < (VOCAB + 63) / 64; item += nblk) {
    __syncthreads();
    const int col0 = item * 64;
    const int wm = (wid >> 1) * 32, wn = (wid & 1) * 32;
    f32x4 acc[2][2] = {};
    const int ar  = tid >> 2;
    const int akc = (tid & 3) * 8;
    const int bkk = tid >> 4;
    const int bn  = (tid & 15) * 4;
    const int gn  = col0 + bn;
    const bool okb = (gn + 3 < VOCAB);
    f32x4 pa0[2], pa1[2], pb0[2], pb1[2];
    auto LOAD = [&](int k0, int s) {
      const float* ap = hout + (size_t)ar * UNITS + k0 + akc;
      pa0[s] = *reinterpret_cast<const f32x4*>(ap);
      pa1[s] = *reinterpret_cast<const f32x4*>(ap + 4);
      const float* bp0 = fcW + (size_t)(k0 + bkk) * VOCAB + gn;
      const float* bp1 = bp0 + (size_t)16 * VOCAB;
      if (okb) {
        pb0[s] = *reinterpret_cast<const f32x4u*>(bp0);
        pb1[s] = *reinterpret_cast<const f32x4u*>(bp1);
      } else {
        f32x4 t0 = {0,0,0,0}, t1 = {0,0,0,0};
#pragma unroll
        for (int j = 0; j < 4; ++j)
          if (gn + j < VOCAB) { t0[j] = bp0[j]; t1[j] = bp1[j]; }
        pb0[s] = t0; pb1[s] = t1;
      }
    };
    auto STAGE = [&](int s, int bb) {
      bf16x8 v;
#pragma unroll
      for (int j = 0; j < 4; ++j) { v[j] = (__bf16)pa0[s][j]; v[4 + j] = (__bf16)pa1[s][j]; }
      *reinterpret_cast<bf16x8*>(&sm.gm.A[bb][tid & 3][ar][0]) = v;
#pragma unroll
      for (int j = 0; j < 4; ++j) {
        sm.gm.B[bb][bkk >> 3][bn + j][bkk & 7]               = (__bf16)pb0[s][j];
        sm.gm.B[bb][(bkk + 16) >> 3][bn + j][(bkk + 16) & 7] = (__bf16)pb1[s][j];
      }
    };
    auto COMPUTE = [&](int bb) {
      bf16x8 af[2], bfr[2];
#pragma unroll
      for (int f = 0; f < 2; ++f) {
        af[f]  = *reinterpret_cast<const bf16x8*>(&sm.gm.A[bb][lane >> 4][wm + f * 16 + (lane & 15)][0]);
        bfr[f] = *reinterpret_cast<const bf16x8*>(&sm.gm.B[bb][lane >> 4][wn + f * 16 + (lane & 15)][0]);
      }
#pragma unroll
      for (int fm = 0; fm < 2; ++fm)
#pragma unroll
        for (int fn = 0; fn < 2; ++fn)
          acc[fm][fn] = __builtin_amdgcn_mfma_f32_16x16x32_bf16(af[fm], bfr[fn], acc[fm][fn], 0, 0, 0);
    };
    LOAD(0, 0); LOAD(32, 1); STAGE(0, 0);
    __syncthreads();
#pragma unroll 1
    for (int t = 0; t < 32; t += 2) {
      if (t + 2 < 32) LOAD((t + 2) << 5, 0);
      COMPUTE(0);
      STAGE(1, 1);
      __syncthreads();
      if (t + 3 < 32) LOAD((t + 3) << 5, 1);
      COMPUTE(1);
      if (t + 2 < 32) STAGE(0, 0);
      __syncthreads();
    }
#pragma unroll
    for (int fm = 0; fm < 2; ++fm) {
      const int rbase = wm + fm * 16 + (lane >> 4) * 4;
#pragma unroll
      for (int fn = 0; fn < 2; ++fn) {
        const int gc = col0 + wn + fn * 16 + (lane & 15);
        if (gc >= VOCAB) continue;
        const float bv = fcb[gc];
#pragma unroll
        for (int r = 0; r < 4; ++r)
          __builtin_nontemporal_store(acc[fm][fn][r] + bv, &logits[(size_t)(rbase + r) * VOCAB + gc]);
      }
    }
  }
}

// ===========================================================================
extern "C" void kernel_launch(void* const* d_in, const int* in_sizes, int n_in,
                              void* d_out, int out_size, void* d_ws, size_t ws_size,
                              hipStream_t stream)
{
  (void)in_sizes; (void)n_in; (void)out_size; (void)ws_size;
  const int*   x      = (const int*)  d_in[0];
  const float* hidden = (const float*)d_in[1];
  const float* enc    = (const float*)d_in[2];
  const float* emb    = (const float*)d_in[3];
  const float* W1     = (const float*)d_in[4];
  const float* b1     = (const float*)d_in[5];
  const float* W2     = (const float*)d_in[6];
  const float* b2     = (const float*)d_in[7];
  const float* Vw     = (const float*)d_in[8];
  const float* bV     = (const float*)d_in[9];
  const float* gk     = (const float*)d_in[10];
  const float* gb     = (const float*)d_in[12];
  const float* fcW    = (const float*)d_in[13];
  const float* fcb    = (const float*)d_in[14];

  float* ws      = (float*)d_ws;
  float* qpart   = ws;                          // 8*64*1024
  float* partial = qpart + 524288;              // 8*8192
  float* xin     = partial + 65536;             // 64*1280
  float* gpart   = xin + 81920;                 // 8*64*3072
  __bf16* encb   = (__bf16*)(gpart + 1572864);  // 8192*1024 bf16
  __bf16* w2t    = encb + (size_t)MROWS * UNITS;// 1024*1024 bf16

  float* out    = (float*)d_out;
  float* logits = out;
  float* hout   = out + (size_t)BATCH * VOCAB;
  float* attw   = hout + BATCH * UNITS;

  // ---- try cooperative path (query occupancy first, verify launch rc) ----
  int maxPerCU = 0;
  hipError_t qe = hipOccupancyMaxActiveBlocksPerMultiprocessor(
      &maxPerCU, reinterpret_cast<const void*>(mega_kernel), 256, 0);
  hipError_t le = hipErrorUnknown;
  if (qe == hipSuccess && maxPerCU >= 2) {
    void* args[] = {
      (void*)&x, (void*)&hidden, (void*)&enc, (void*)&emb,
      (void*)&W1, (void*)&b1, (void*)&W2, (void*)&b2,
      (void*)&Vw, (void*)&bV, (void*)&gk, (void*)&gb,
      (void*)&fcW, (void*)&fcb,
      (void*)&encb, (void*)&w2t, (void*)&qpart, (void*)&partial,
      (void*)&xin, (void*)&gpart, (void*)&logits, (void*)&hout, (void*)&attw
    };
    le = hipLaunchCooperativeKernel(reinterpret_cast<const void*>(mega_kernel),
                                    dim3(NBLK), dim3(256), args, 0, stream);
  }
  if (le == hipSuccess) return;

  // ---- fallback: proven 6-kernel path (R8 config, 143.2 µs) ----
  hipLaunchKernelGGL(prep_kernel, dim3(4096 + 256 + 128), dim3(256), 0, stream,
                     enc, W2, hidden, W1, encb, w2t, qpart);
  hipLaunchKernelGGL(k_score_mfma, dim3(64, NCB), dim3(256), 0, stream,
                     encb, w2t, b1, b2, qpart, Vw, partial);
  hipLaunchKernelGGL(ctx_kernel, dim3(64, 16), dim3(256), 0, stream,
                     enc, partial, bV, emb, x, attw, xin);
  hipLaunchKernelGGL(gemm_splitk, dim3(1, 48, NSPLIT), dim3(256), 0, stream,
                     xin, gk, gpart, 64, 3072, 1280, 160);
  hipLaunchKernelGGL(gru_pw, dim3(256), dim3(256), 0, stream,
                     gpart, gb, gb + 3072, hout);
  hipLaunchKernelGGL(gemm_fc, dim3((VOCAB + 63) / 64), dim3(256), 0, stream,
                     hout, fcW, fcb, logits, VOCAB);
}